// Round 6
// baseline (142.835 us; speedup 1.0000x reference)
//
#include <hip/hip_runtime.h>
#include <stdint.h>

typedef short short8 __attribute__((ext_vector_type(8)));
typedef float floatx4 __attribute__((ext_vector_type(4)));

#define BIAS 8.0f

__device__ __forceinline__ unsigned short f2bf(float f) {
    unsigned int u = __float_as_uint(f);
    unsigned int r = (u + 0x7FFFu + ((u >> 16) & 1u)) >> 16;   // RNE
    return (unsigned short)r;
}

// ---------------- kernel 0: W -> bf16(-w) in MFMA-B-fragment order, + zero loss slot
// short8 slot s: T=s>>7 (16-code tile), h=(s>>6)&1 (k half), l=s&63 (lane)
// value[j] = -W[T*16 + (l&15)][h*32 + (l>>4)*8 + j]
__global__ void vq_prep(const float* __restrict__ W, unsigned short* __restrict__ Wsw,
                        float* __restrict__ out0) {
    const int s = blockIdx.x * 256 + threadIdx.x;      // 32768 slots
    const int T = s >> 7;
    const int h = (s >> 6) & 1;
    const int l = s & 63;
    const int code = T * 16 + (l & 15);
    const float* src = W + code * 64 + h * 32 + (l >> 4) * 8;
    const floatx4* sp = (const floatx4*)src;
    floatx4 f0 = sp[0], f1 = sp[1];
    short8 fr;
    fr[0] = (short)f2bf(-f0[0]); fr[1] = (short)f2bf(-f0[1]);
    fr[2] = (short)f2bf(-f0[2]); fr[3] = (short)f2bf(-f0[3]);
    fr[4] = (short)f2bf(-f1[0]); fr[5] = (short)f2bf(-f1[1]);
    fr[6] = (short)f2bf(-f1[2]); fr[7] = (short)f2bf(-f1[3]);
    ((short8*)Wsw)[s] = fr;
    if (s == 0) *out0 = 0.0f;
}

// ---------------- kernel 1: block = 32 rows; 4 waves = 2 rowhalves x 2 codehalves
// wave = 1 M-tile (16 rows) x 2048 codes. ~50 VGPR -> 8 waves/EU, 32 waves/CU.
__launch_bounds__(256)
__attribute__((amdgpu_waves_per_eu(8, 8)))
__global__ void vq_main(const float* __restrict__ z, const float* __restrict__ W,
                        const unsigned short* __restrict__ Wsw, float* __restrict__ out) {
    __shared__ unsigned int pk2[64];   // [row 0..31][codehalf]
    __shared__ float ls[4];

    const int tid  = threadIdx.x;
    const int lane = tid & 63;
    const int wave = tid >> 6;
    const int rh   = wave >> 1;        // row half  (16 rows each)
    const int ch   = wave & 1;         // code half (2048 codes each)
    const int l15  = lane & 15;
    const int lq   = lane >> 4;
    const int rowbase = blockIdx.x * 32;

    // ---- A fragments: 16 rows x 64 k as bf16 (8 VGPR)
    short8 afrag[2];
    {
        const float* zp = z + (rowbase + rh * 16 + l15) * 64 + lq * 8;
        #pragma unroll
        for (int h = 0; h < 2; ++h) {
            const floatx4* p = (const floatx4*)(zp + h * 32);
            floatx4 f0 = p[0], f1 = p[1];
            short8 fr;
            fr[0] = (short)f2bf(f0[0]); fr[1] = (short)f2bf(f0[1]);
            fr[2] = (short)f2bf(f0[2]); fr[3] = (short)f2bf(f0[3]);
            fr[4] = (short)f2bf(f1[0]); fr[5] = (short)f2bf(f1[1]);
            fr[6] = (short)f2bf(f1[2]); fr[7] = (short)f2bf(f1[3]);
            afrag[h] = fr;
        }
    }

    const floatx4 bias4 = {BIAS, BIAS, BIAS, BIAS};
    unsigned int minpk[4] = {0xFFFFFFFFu, 0xFFFFFFFFu, 0xFFFFFFFFu, 0xFFFFFFFFu};

    // ---- K loop: 64 iterations x 2 code-tiles; 4 independent loads per iteration
    const short8* __restrict__ bp = (const short8*)Wsw + ch * 16384 + lane;
    unsigned int kidx = (unsigned int)(ch * 2048 + l15);
    #pragma unroll 2
    for (int it = 0; it < 64; ++it) {
        short8 b00 = bp[0];
        short8 b01 = bp[64];
        short8 b10 = bp[128];
        short8 b11 = bp[192];
        bp += 256;
        floatx4 acc0 = __builtin_amdgcn_mfma_f32_16x16x32_bf16(afrag[0], b00, bias4, 0, 0, 0);
        acc0 = __builtin_amdgcn_mfma_f32_16x16x32_bf16(afrag[1], b01, acc0, 0, 0, 0);
        floatx4 acc1 = __builtin_amdgcn_mfma_f32_16x16x32_bf16(afrag[0], b10, bias4, 0, 0, 0);
        acc1 = __builtin_amdgcn_mfma_f32_16x16x32_bf16(afrag[1], b11, acc1, 0, 0, 0);
        #pragma unroll
        for (int r = 0; r < 4; ++r) {
            unsigned int p0 = __float_as_uint(acc0[r]) | kidx;          // monotone pack
            unsigned int p1 = __float_as_uint(acc1[r]) | (kidx + 16u);
            unsigned int pm = p0 < p1 ? p0 : p1;
            minpk[r] = pm < minpk[r] ? pm : minpk[r];                   // -> v_min3_u32
        }
        kidx += 32;
    }

    // ---- reduce across the 16 code-columns (lane bits 0..3), publish per-row mins
    #pragma unroll
    for (int r = 0; r < 4; ++r) {
        unsigned int v = minpk[r];
        #pragma unroll
        for (int m = 1; m < 16; m <<= 1) {
            unsigned int o = (unsigned int)__shfl_xor((int)v, m, 64);
            v = o < v ? o : v;
        }
        if (l15 == 0) pk2[(rh * 16 + lq * 4 + r) * 2 + ch] = v;
    }
    __syncthreads();

    // ---- epilogue: 8 threads per row (32 rows), gather W[idx] fp32, write z_q, loss
    const int r32 = tid >> 3;            // 0..31
    const int seg = tid & 7;             // 8-float segment
    unsigned int va = pk2[r32 * 2], vb = pk2[r32 * 2 + 1];
    unsigned int idx = (va < vb ? va : vb) & 0xFFFu;
    const int row = rowbase + r32;

    float loss = 0.0f;
    {
        const floatx4* wp = (const floatx4*)(W + idx * 64 + seg * 8);
        const floatx4* zp = (const floatx4*)(z + row * 64 + seg * 8);
        floatx4* op = (floatx4*)(out + 1 + row * 64 + seg * 8);
        #pragma unroll
        for (int part = 0; part < 2; ++part) {
            floatx4 wv = wp[part];
            floatx4 zv = zp[part];
            op[part] = wv;
            #pragma unroll
            for (int j = 0; j < 4; ++j) {
                float d = zv[j] - wv[j];
                loss = fmaf(d, d, loss);
            }
        }
    }
    #pragma unroll
    for (int m = 1; m < 64; m <<= 1) loss += __shfl_xor(loss, m, 64);
    if (lane == 0) ls[wave] = loss;
    __syncthreads();
    if (tid == 0) {
        float t = (ls[0] + ls[1]) + (ls[2] + ls[3]);
        atomicAdd(out, t * (0.25f / 4194304.0f));
    }
}

extern "C" void kernel_launch(void* const* d_in, const int* in_sizes, int n_in,
                              void* d_out, int out_size, void* d_ws, size_t ws_size,
                              hipStream_t stream) {
    (void)in_sizes; (void)n_in; (void)out_size; (void)ws_size;
    const float* z = (const float*)d_in[0];
    const float* W = (const float*)d_in[1];
    unsigned short* Wsw = (unsigned short*)d_ws;     // 512 KB: bf16(-w), B-frag order
    float* out = (float*)d_out;

    vq_prep<<<128, 256, 0, stream>>>(W, Wsw, out);
    vq_main<<<2048, 256, 0, stream>>>(z, W, Wsw, out);
}

// Round 7
// 126.704 us; speedup vs baseline: 1.1273x; 1.1273x over previous
//
#include <hip/hip_runtime.h>
#include <stdint.h>

typedef short short8 __attribute__((ext_vector_type(8)));
typedef float floatx4 __attribute__((ext_vector_type(4)));

#define BIAS 8.0f

__device__ __forceinline__ unsigned short f2bf(float f) {
    unsigned int u = __float_as_uint(f);
    unsigned int r = (u + 0x7FFFu + ((u >> 16) & 1u)) >> 16;   // RNE
    return (unsigned short)r;
}

// async global->LDS DMA, 16 B per lane; LDS dest = wave-uniform base + lane*16
__device__ __forceinline__ void gload_lds16(const void* g, void* l) {
    __builtin_amdgcn_global_load_lds(
        (const __attribute__((address_space(1))) unsigned int*)g,
        (__attribute__((address_space(3))) unsigned int*)l, 16, 0, 0);
}

// ---------------- kernel 0: W -> bf16(-w) in MFMA-B-fragment order, + zero loss slot
// short8 slot s: T=s>>7 (16-code tile), h=(s>>6)&1 (k half), l=s&63 (lane)
// value[j] = -W[T*16 + (l&15)][h*32 + (l>>4)*8 + j]
__global__ void vq_prep(const float* __restrict__ W, unsigned short* __restrict__ Wsw,
                        float* __restrict__ out0) {
    const int s = blockIdx.x * 256 + threadIdx.x;      // 32768 slots
    const int T = s >> 7;
    const int h = (s >> 6) & 1;
    const int l = s & 63;
    const int code = T * 16 + (l & 15);
    const float* src = W + code * 64 + h * 32 + (l >> 4) * 8;
    const floatx4* sp = (const floatx4*)src;
    floatx4 f0 = sp[0], f1 = sp[1];
    short8 fr;
    fr[0] = (short)f2bf(-f0[0]); fr[1] = (short)f2bf(-f0[1]);
    fr[2] = (short)f2bf(-f0[2]); fr[3] = (short)f2bf(-f0[3]);
    fr[4] = (short)f2bf(-f1[0]); fr[5] = (short)f2bf(-f1[1]);
    fr[6] = (short)f2bf(-f1[2]); fr[7] = (short)f2bf(-f1[3]);
    ((short8*)Wsw)[s] = fr;
    if (s == 0) *out0 = 0.0f;
}

// ---------------- kernel 1: m97-pattern. block = 64 rows, 4 waves share rows;
// each wave consumes a different 32-code quarter of each 128-code LDS chunk.
__launch_bounds__(256)
__global__ void vq_main(const float* __restrict__ z, const float* __restrict__ W,
                        const unsigned short* __restrict__ Wsw, float* __restrict__ out) {
    __shared__ __align__(16) unsigned short Bbuf[2][8192];   // 2 x 16 KB chunks
    __shared__ unsigned int pk_lds[256];                     // [wave][row 0..63]
    __shared__ float ls[4];

    const int tid  = threadIdx.x;
    const int lane = tid & 63;
    const int wave = tid >> 6;
    const int l15  = lane & 15;
    const int lq   = lane >> 4;
    const int rowbase = blockIdx.x * 64;

    // ---- stage chunk 0 (async DMA) before touching z
    {
        const char* g = (const char*)Wsw + wave * 1024 + lane * 16;
        char* l = (char*)&Bbuf[0][0] + wave * 1024;
        #pragma unroll
        for (int i = 0; i < 4; ++i)
            gload_lds16(g + i * 4096, l + i * 4096);
    }

    // ---- A fragments: the block's 64 rows x 64 k as bf16 (32 VGPR), all waves same rows
    short8 afrag[4][2];
    #pragma unroll
    for (int mt = 0; mt < 4; ++mt) {
        const float* zp = z + (rowbase + mt * 16 + l15) * 64 + lq * 8;
        #pragma unroll
        for (int h = 0; h < 2; ++h) {
            const floatx4* p = (const floatx4*)(zp + h * 32);
            floatx4 f0 = p[0], f1 = p[1];
            short8 fr;
            fr[0] = (short)f2bf(f0[0]); fr[1] = (short)f2bf(f0[1]);
            fr[2] = (short)f2bf(f0[2]); fr[3] = (short)f2bf(f0[3]);
            fr[4] = (short)f2bf(f1[0]); fr[5] = (short)f2bf(f1[1]);
            fr[6] = (short)f2bf(f1[2]); fr[7] = (short)f2bf(f1[3]);
            afrag[mt][h] = fr;
        }
    }

    const floatx4 bias4 = {BIAS, BIAS, BIAS, BIAS};
    unsigned int minpk[4][4];
    #pragma unroll
    for (int mt = 0; mt < 4; ++mt)
        #pragma unroll
        for (int r = 0; r < 4; ++r) minpk[mt][r] = 0xFFFFFFFFu;

    __syncthreads();   // chunk 0 staged

    // ---- 32 chunks of 128 codes; double-buffered async DMA, 1 barrier/chunk
    const unsigned int kw = (unsigned int)(wave * 32 + l15);
    for (int cb = 0; cb < 32; ++cb) {
        if (cb < 31) {   // stage next chunk into the other buffer
            const char* g = (const char*)Wsw + (cb + 1) * 16384 + wave * 1024 + lane * 16;
            char* l = (char*)&Bbuf[(cb + 1) & 1][0] + wave * 1024;
            #pragma unroll
            for (int i = 0; i < 4; ++i)
                gload_lds16(g + i * 4096, l + i * 4096);
        }
        const unsigned short* bb = &Bbuf[cb & 1][0];
        #pragma unroll
        for (int t = 0; t < 2; ++t) {
            const int tl = wave * 2 + t;                       // local tile 0..7
            const short8* tp = (const short8*)(bb + tl * 1024);
            short8 b0 = tp[lane];
            short8 b1 = tp[64 + lane];
            const unsigned int kk = (unsigned int)(cb * 128 + t * 16) + kw;
            #pragma unroll
            for (int mt = 0; mt < 4; ++mt) {
                floatx4 acc = __builtin_amdgcn_mfma_f32_16x16x32_bf16(afrag[mt][0], b0, bias4, 0, 0, 0);
                acc = __builtin_amdgcn_mfma_f32_16x16x32_bf16(afrag[mt][1], b1, acc, 0, 0, 0);
                #pragma unroll
                for (int r = 0; r < 4; ++r) {
                    unsigned int p = __float_as_uint(acc[r]) | kk;   // monotone pack
                    minpk[mt][r] = p < minpk[mt][r] ? p : minpk[mt][r];
                }
            }
        }
        __syncthreads();   // drains DMA (next chunk ready) + joins consumers
    }

    // ---- reduce across the 16 code-columns (lane bits 0..3), publish per-wave mins
    #pragma unroll
    for (int mt = 0; mt < 4; ++mt)
        #pragma unroll
        for (int r = 0; r < 4; ++r) {
            unsigned int v = minpk[mt][r];
            #pragma unroll
            for (int m = 1; m < 16; m <<= 1) {
                unsigned int o = (unsigned int)__shfl_xor((int)v, m, 64);
                v = o < v ? o : v;
            }
            if (l15 == 0) pk_lds[wave * 64 + mt * 16 + lq * 4 + r] = v;
        }
    __syncthreads();

    // ---- epilogue: wave w owns rows w*16 .. w*16+15 (of the block's 64)
    const int rl  = wave * 16 + l15;
    unsigned int v0 = pk_lds[rl];
    unsigned int v1 = pk_lds[64 + rl];
    unsigned int v2 = pk_lds[128 + rl];
    unsigned int v3 = pk_lds[192 + rl];
    unsigned int vm = v0 < v1 ? v0 : v1;
    unsigned int vn = v2 < v3 ? v2 : v3;
    unsigned int idx = (vm < vn ? vm : vn) & 0xFFFu;

    const int row = rowbase + rl;
    float loss = 0.0f;
    #pragma unroll
    for (int h = 0; h < 2; ++h) {
        const floatx4* wp = (const floatx4*)(W + idx * 64 + h * 32 + lq * 8);
        const floatx4* zp = (const floatx4*)(z + row * 64 + h * 32 + lq * 8);
        floatx4* op = (floatx4*)(out + 1 + row * 64 + h * 32 + lq * 8);
        #pragma unroll
        for (int part = 0; part < 2; ++part) {
            floatx4 wv = wp[part];
            floatx4 zv = zp[part];
            op[part] = wv;
            #pragma unroll
            for (int j = 0; j < 4; ++j) {
                float d = zv[j] - wv[j];
                loss = fmaf(d, d, loss);
            }
        }
    }
    #pragma unroll
    for (int m = 1; m < 64; m <<= 1) loss += __shfl_xor(loss, m, 64);
    if (lane == 0) ls[wave] = loss;
    __syncthreads();
    if (tid == 0) {
        float t = (ls[0] + ls[1]) + (ls[2] + ls[3]);
        atomicAdd(out, t * (0.25f / 4194304.0f));
    }
}

extern "C" void kernel_launch(void* const* d_in, const int* in_sizes, int n_in,
                              void* d_out, int out_size, void* d_ws, size_t ws_size,
                              hipStream_t stream) {
    (void)in_sizes; (void)n_in; (void)out_size; (void)ws_size;
    const float* z = (const float*)d_in[0];
    const float* W = (const float*)d_in[1];
    unsigned short* Wsw = (unsigned short*)d_ws;     // 512 KB: bf16(-w), B-frag order
    float* out = (float*)d_out;

    vq_prep<<<128, 256, 0, stream>>>(W, Wsw, out);
    vq_main<<<1024, 256, 0, stream>>>(z, W, Wsw, out);
}

// Round 8
// 118.390 us; speedup vs baseline: 1.2065x; 1.0702x over previous
//
#include <hip/hip_runtime.h>
#include <stdint.h>

typedef int   int4v  __attribute__((ext_vector_type(4)));
typedef int   int8v  __attribute__((ext_vector_type(8)));
typedef float floatx4 __attribute__((ext_vector_type(4)));
typedef float float16v __attribute__((ext_vector_type(16)));

#define BIAS 128.0f

// async global->LDS DMA, 16 B per lane; LDS dest = wave-uniform base + lane*16
__device__ __forceinline__ void gload_lds16(const void* g, void* l) {
    __builtin_amdgcn_global_load_lds(
        (const __attribute__((address_space(1))) unsigned int*)g,
        (__attribute__((address_space(3))) unsigned int*)l, 16, 0, 0);
}

// ---------------- kernel 0: W -> fp8(-4096*w) in 32x32x64 B-frag order,
// init minidx to +inf, zero loss slot.
// Layout: tile T (codes 32T..32T+31), chunk q (k-bytes q*16..q*16+15), lane l:
//   byte addr = T*2048 + q*1024 + l*16 + p ;  c = 32T+(l&31), k = (l>>5)*32 + q*16 + p
__global__ void vq_prep(const float* __restrict__ W, unsigned char* __restrict__ Wsw,
                        unsigned int* __restrict__ minidx, float* __restrict__ out0) {
    const int s = blockIdx.x * 256 + threadIdx.x;   // 16384 slots of 16 B
    const int T = s >> 7;
    const int q = (s >> 6) & 1;
    const int l = s & 63;
    const int c  = T * 32 + (l & 31);
    const int kb = (l >> 5) * 32 + q * 16;
    const floatx4* wp = (const floatx4*)(W + c * 64 + kb);
    int4v d;
    #pragma unroll
    for (int i = 0; i < 4; ++i) {
        floatx4 f = wp[i];
        int w_ = __builtin_amdgcn_cvt_pk_fp8_f32(f[0] * -4096.0f, f[1] * -4096.0f, 0, false);
        w_ = __builtin_amdgcn_cvt_pk_fp8_f32(f[2] * -4096.0f, f[3] * -4096.0f, w_, true);
        d[i] = w_;
    }
    ((int4v*)Wsw)[s] = d;
    int4v inf = {(int)0xFFFFFFFF, (int)0xFFFFFFFF, (int)0xFFFFFFFF, (int)0xFFFFFFFF};
    ((int4v*)minidx)[s] = inf;                      // 4 rows per thread
    if (s == 0) *out0 = 0.0f;
}

// ---------------- kernel 1: block = 512 rows x 1024 codes (cg). B lives in LDS
// for the whole kernel (loaded once, no K-loop barriers). wave = 64 rows.
__launch_bounds__(512)
__attribute__((amdgpu_waves_per_eu(4)))
__global__ void vq_main(const float* __restrict__ z, const unsigned char* __restrict__ Wsw,
                        unsigned int* __restrict__ minidx) {
    __shared__ __align__(16) unsigned char B[65536];

    const int tid  = threadIdx.x;
    const int lane = tid & 63;
    const int wave = tid >> 6;          // 0..7
    const int cg     = blockIdx.x & 3;  // code group (1024 codes)
    const int rowblk = blockIdx.x >> 2; // 0..127 (512 rows each)
    const int l31 = lane & 31;
    const int lh  = lane >> 5;

    // ---- stage this cg's 64 KB of B once (async DMA, linear copy)
    #pragma unroll
    for (int i = 0; i < 8; ++i) {
        const int off = (wave * 8 + i) * 1024 + lane * 16;
        gload_lds16(Wsw + cg * 65536 + off, B + off);
    }

    // ---- A fragments: 64 rows as fp8 (2 M-tiles of 32); lane: row=l&31, k=(l>>5)*32+j
    const int rowwave = rowblk * 512 + wave * 64;
    int8v afrag[2];
    #pragma unroll
    for (int mt = 0; mt < 2; ++mt) {
        const floatx4* zp = (const floatx4*)(z + (rowwave + mt * 32 + l31) * 64 + lh * 32);
        int8v fr;
        #pragma unroll
        for (int d = 0; d < 8; ++d) {
            floatx4 v = zp[d];
            int w_ = __builtin_amdgcn_cvt_pk_fp8_f32(v[0], v[1], 0, false);
            w_ = __builtin_amdgcn_cvt_pk_fp8_f32(v[2], v[3], w_, true);
            fr[d] = w_;
        }
        afrag[mt] = fr;
    }

    float16v bias;
    #pragma unroll
    for (int i = 0; i < 16; ++i) bias[i] = BIAS;

    unsigned int minpk[2][16];
    #pragma unroll
    for (int mt = 0; mt < 2; ++mt)
        #pragma unroll
        for (int r = 0; r < 16; ++r) minpk[mt][r] = 0xFFFFFFFFu;

    __syncthreads();    // B staged (drains DMA)

    // ---- K loop: 32 tiles of 32 codes, all from LDS; 1 MFMA (K=64) per M-tile
    const unsigned int kk0 = (unsigned int)(cg * 1024 + l31);
    #pragma unroll 2
    for (int t = 0; t < 32; ++t) {
        int4v b0 = *(const int4v*)(B + t * 2048 + lane * 16);
        int4v b1 = *(const int4v*)(B + t * 2048 + 1024 + lane * 16);
        int8v b = {b0[0], b0[1], b0[2], b0[3], b1[0], b1[1], b1[2], b1[3]};
        const unsigned int kk = kk0 + (unsigned int)(t * 32);
        #pragma unroll
        for (int mt = 0; mt < 2; ++mt) {
            float16v acc = __builtin_amdgcn_mfma_scale_f32_32x32x64_f8f6f4(
                afrag[mt], b, bias, 0, 0, 0, 0x7F7F7F7F, 0, 0x7F7F7F7F);
            #pragma unroll
            for (int r = 0; r < 16; ++r) {
                unsigned int p = __float_as_uint(acc[r]) | kk;   // monotone pack
                minpk[mt][r] = p < minpk[mt][r] ? p : minpk[mt][r];
            }
        }
    }

    // ---- butterfly allreduce over the 32 code-columns, then atomicMin per row.
    // D layout (32x32): col = lane&31, row = (r&3) + 8*(r>>2) + 4*(lane>>5)
    #pragma unroll
    for (int mt = 0; mt < 2; ++mt)
        #pragma unroll
        for (int r = 0; r < 16; ++r) {
            unsigned int v = minpk[mt][r];
            #pragma unroll
            for (int m = 1; m < 32; m <<= 1) {
                unsigned int o = (unsigned int)__shfl_xor((int)v, m, 64);
                v = o < v ? o : v;
            }
            if (l31 == r) {
                const int row = rowwave + mt * 32 + (r & 3) + 8 * (r >> 2) + 4 * lh;
                atomicMin(&minidx[row], v);
            }
        }
}

// ---------------- kernel 2: gather W[idx] fp32, write z_q, accumulate loss
__launch_bounds__(256)
__global__ void vq_out(const float* __restrict__ z, const float* __restrict__ W,
                       const unsigned int* __restrict__ minidx, float* __restrict__ out) {
    __shared__ float ls[4];
    const int g = blockIdx.x * 256 + threadIdx.x;   // 262144 = rows*4
    const int row = g >> 2;
    const int seg = g & 3;                          // 16-float segment
    const unsigned int idx = minidx[row] & 0xFFFu;

    const floatx4* wp = (const floatx4*)(W + idx * 64 + seg * 16);
    const floatx4* zp = (const floatx4*)(z + row * 64 + seg * 16);
    floatx4* op = (floatx4*)(out + 1 + row * 64 + seg * 16);
    float loss = 0.0f;
    #pragma unroll
    for (int p2 = 0; p2 < 4; ++p2) {
        floatx4 wv = wp[p2];
        floatx4 zv = zp[p2];
        op[p2] = wv;
        #pragma unroll
        for (int j = 0; j < 4; ++j) {
            float d = zv[j] - wv[j];
            loss = fmaf(d, d, loss);
        }
    }
    #pragma unroll
    for (int m = 1; m < 64; m <<= 1) loss += __shfl_xor(loss, m, 64);
    const int lane = threadIdx.x & 63, wave = threadIdx.x >> 6;
    if (lane == 0) ls[wave] = loss;
    __syncthreads();
    if (threadIdx.x == 0) {
        float t = (ls[0] + ls[1]) + (ls[2] + ls[3]);
        atomicAdd(out, t * (0.25f / 4194304.0f));
    }
}

extern "C" void kernel_launch(void* const* d_in, const int* in_sizes, int n_in,
                              void* d_out, int out_size, void* d_ws, size_t ws_size,
                              hipStream_t stream) {
    (void)in_sizes; (void)n_in; (void)out_size; (void)ws_size;
    const float* z = (const float*)d_in[0];
    const float* W = (const float*)d_in[1];
    unsigned char* Wsw = (unsigned char*)d_ws;                       // 256 KB fp8 table
    unsigned int* minidx = (unsigned int*)((char*)d_ws + 262144);    // 256 KB packed mins
    float* out = (float*)d_out;

    vq_prep<<<64, 256, 0, stream>>>(W, Wsw, minidx, out);
    vq_main<<<512, 512, 0, stream>>>(z, Wsw, minidx);
    vq_out<<<1024, 256, 0, stream>>>(z, W, minidx, out);
}

// Round 9
// 116.618 us; speedup vs baseline: 1.2248x; 1.0152x over previous
//
#include <hip/hip_runtime.h>
#include <stdint.h>

typedef int   int4v  __attribute__((ext_vector_type(4)));
typedef int   int8v  __attribute__((ext_vector_type(8)));
typedef float floatx4 __attribute__((ext_vector_type(4)));
typedef float float16v __attribute__((ext_vector_type(16)));

#define BIAS 128.0f

// async global->LDS DMA, 16 B per lane; LDS dest = wave-uniform base + lane*16
__device__ __forceinline__ void gload_lds16(const void* g, void* l) {
    __builtin_amdgcn_global_load_lds(
        (const __attribute__((address_space(1))) unsigned int*)g,
        (__attribute__((address_space(3))) unsigned int*)l, 16, 0, 0);
}

// ---------------- kernel 0: W -> fp8(-4096*w) in 32x32x64 B-frag order,
// init minidx to +inf, zero loss slot.
// Layout: tile T (codes 32T..32T+31), chunk q (k-bytes q*16..q*16+15), lane l:
//   byte addr = T*2048 + q*1024 + l*16 + p ;  c = 32T+(l&31), k = (l>>5)*32 + q*16 + p
__global__ void vq_prep(const float* __restrict__ W, unsigned char* __restrict__ Wsw,
                        unsigned int* __restrict__ minidx, float* __restrict__ out0) {
    const int s = blockIdx.x * 256 + threadIdx.x;   // 16384 slots of 16 B
    const int T = s >> 7;
    const int q = (s >> 6) & 1;
    const int l = s & 63;
    const int c  = T * 32 + (l & 31);
    const int kb = (l >> 5) * 32 + q * 16;
    const floatx4* wp = (const floatx4*)(W + c * 64 + kb);
    int4v d;
    #pragma unroll
    for (int i = 0; i < 4; ++i) {
        floatx4 f = wp[i];
        int w_ = __builtin_amdgcn_cvt_pk_fp8_f32(f[0] * -4096.0f, f[1] * -4096.0f, 0, false);
        w_ = __builtin_amdgcn_cvt_pk_fp8_f32(f[2] * -4096.0f, f[3] * -4096.0f, w_, true);
        d[i] = w_;
    }
    ((int4v*)Wsw)[s] = d;
    int4v inf = {(int)0xFFFFFFFF, (int)0xFFFFFFFF, (int)0xFFFFFFFF, (int)0xFFFFFFFF};
    ((int4v*)minidx)[s] = inf;                      // 4 rows per thread
    if (s == 0) *out0 = 0.0f;
}

// ---------------- kernel 1: block = 256 rows x 1024 codes (cg); 8 waves,
// wave = ONE 32x32 M-tile (32 rows). B resident in LDS, no K-loop barriers.
// Register budget: afrag 8 + minpk 16 + acc 16x2 + bias 16 + b 16 + misc ~ 105.
__launch_bounds__(512)
__attribute__((amdgpu_waves_per_eu(4, 4)))
__global__ void vq_main(const float* __restrict__ z, const unsigned char* __restrict__ Wsw,
                        unsigned int* __restrict__ minidx) {
    __shared__ __align__(16) unsigned char B[65536];

    const int tid  = threadIdx.x;
    const int lane = tid & 63;
    const int wave = tid >> 6;          // 0..7
    const int cg     = blockIdx.x & 3;  // code group (1024 codes)
    const int rowblk = blockIdx.x >> 2; // 0..255 (256 rows each)
    const int l31 = lane & 31;
    const int lh  = lane >> 5;

    // ---- stage this cg's 64 KB of B once (async DMA, linear copy)
    #pragma unroll
    for (int i = 0; i < 8; ++i) {
        const int off = (wave * 8 + i) * 1024 + lane * 16;
        gload_lds16(Wsw + cg * 65536 + off, B + off);
    }

    // ---- A fragment: 32 rows as fp8; lane: row = l&31, k = (l>>5)*32 + j
    const int rowwave = rowblk * 256 + wave * 32;
    int8v afrag;
    {
        const floatx4* zp = (const floatx4*)(z + (rowwave + l31) * 64 + lh * 32);
        #pragma unroll
        for (int d = 0; d < 8; ++d) {
            floatx4 v = zp[d];
            int w_ = __builtin_amdgcn_cvt_pk_fp8_f32(v[0], v[1], 0, false);
            w_ = __builtin_amdgcn_cvt_pk_fp8_f32(v[2], v[3], w_, true);
            afrag[d] = w_;
        }
    }

    float16v bias;
    #pragma unroll
    for (int i = 0; i < 16; ++i) bias[i] = BIAS;

    unsigned int minpk[16];
    #pragma unroll
    for (int r = 0; r < 16; ++r) minpk[r] = 0xFFFFFFFFu;

    __syncthreads();    // B staged (drains DMA)

    // ---- K loop: 32 tiles of 32 codes, all from LDS; one K=64 MFMA per tile
    const unsigned int kk0 = (unsigned int)(cg * 1024 + l31);
    #pragma unroll 2
    for (int t = 0; t < 32; ++t) {
        int8v b;
        *(int4v*)&b       = *(const int4v*)(B + t * 2048 + lane * 16);
        *((int4v*)&b + 1) = *(const int4v*)(B + t * 2048 + 1024 + lane * 16);
        const unsigned int kk = kk0 + (unsigned int)(t * 32);
        float16v acc = __builtin_amdgcn_mfma_scale_f32_32x32x64_f8f6f4(
            afrag, b, bias, 0, 0, 0, 0x7F7F7F7F, 0, 0x7F7F7F7F);
        #pragma unroll
        for (int r = 0; r < 16; ++r) {
            unsigned int p = __float_as_uint(acc[r]) | kk;   // monotone pack
            minpk[r] = p < minpk[r] ? p : minpk[r];
        }
    }

    // ---- butterfly allreduce over the 32 code-columns, then atomicMin per row.
    // D layout (32x32): col = lane&31, row = (r&3) + 8*(r>>2) + 4*(lane>>5)
    #pragma unroll
    for (int r = 0; r < 16; ++r) {
        unsigned int v = minpk[r];
        #pragma unroll
        for (int m = 1; m < 32; m <<= 1) {
            unsigned int o = (unsigned int)__shfl_xor((int)v, m, 64);
            v = o < v ? o : v;
        }
        if (l31 == r) {
            const int row = rowwave + (r & 3) + 8 * (r >> 2) + 4 * lh;
            atomicMin(&minidx[row], v);
        }
    }
}

// ---------------- kernel 2: gather W[idx] fp32, write z_q, accumulate loss
__launch_bounds__(256)
__global__ void vq_out(const float* __restrict__ z, const float* __restrict__ W,
                       const unsigned int* __restrict__ minidx, float* __restrict__ out) {
    __shared__ float ls[4];
    const int g = blockIdx.x * 256 + threadIdx.x;   // 262144 = rows*4
    const int row = g >> 2;
    const int seg = g & 3;                          // 16-float segment
    const unsigned int idx = minidx[row] & 0xFFFu;

    const floatx4* wp = (const floatx4*)(W + idx * 64 + seg * 16);
    const floatx4* zp = (const floatx4*)(z + row * 64 + seg * 16);
    floatx4* op = (floatx4*)(out + 1 + row * 64 + seg * 16);
    float loss = 0.0f;
    #pragma unroll
    for (int p2 = 0; p2 < 4; ++p2) {
        floatx4 wv = wp[p2];
        floatx4 zv = zp[p2];
        op[p2] = wv;
        #pragma unroll
        for (int j = 0; j < 4; ++j) {
            float d = zv[j] - wv[j];
            loss = fmaf(d, d, loss);
        }
    }
    #pragma unroll
    for (int m = 1; m < 64; m <<= 1) loss += __shfl_xor(loss, m, 64);
    const int lane = threadIdx.x & 63, wave = threadIdx.x >> 6;
    if (lane == 0) ls[wave] = loss;
    __syncthreads();
    if (threadIdx.x == 0) {
        float t = (ls[0] + ls[1]) + (ls[2] + ls[3]);
        atomicAdd(out, t * (0.25f / 4194304.0f));
    }
}

extern "C" void kernel_launch(void* const* d_in, const int* in_sizes, int n_in,
                              void* d_out, int out_size, void* d_ws, size_t ws_size,
                              hipStream_t stream) {
    (void)in_sizes; (void)n_in; (void)out_size; (void)ws_size;
    const float* z = (const float*)d_in[0];
    const float* W = (const float*)d_in[1];
    unsigned char* Wsw = (unsigned char*)d_ws;                       // 256 KB fp8 table
    unsigned int* minidx = (unsigned int*)((char*)d_ws + 262144);    // 256 KB packed mins
    float* out = (float*)d_out;

    vq_prep<<<64, 256, 0, stream>>>(W, Wsw, minidx, out);
    vq_main<<<1024, 512, 0, stream>>>(z, Wsw, minidx);
    vq_out<<<1024, 256, 0, stream>>>(z, W, minidx, out);
}